// Round 6
// baseline (1229.524 us; speedup 1.0000x reference)
//
#include <hip/hip_runtime.h>
#include <hip/hip_bf16.h>

// Problem constants (match reference)
#define NN 100000   // nodes
#define NE 400000   // edges per etype
#define NT 3        // etypes
#define NL 3        // layers
#define DD 64       // feature dim
#define M_TOT (NT * NN)             // 300000 concatenated (etype,node) rows
#define NBLK ((M_TOT + 255) / 256)  // 1172 scan blocks

// Data established as fp32 (round-3 runtime dtype detection).

// ---- CSR build (once per launch; dst is layer-invariant) -------------------

__global__ __launch_bounds__(256) void count_kernel(const int* __restrict__ dst,
                                                    int* __restrict__ cnt) {
    int tid = blockIdx.x * 256 + threadIdx.x;
    if (tid >= NT * NE) return;
    int t = tid / NE;
    atomicAdd(&cnt[t * NN + dst[tid]], 1);
}

__global__ __launch_bounds__(256) void bsum_kernel(const int* __restrict__ cnt,
                                                   int* __restrict__ bsums) {
    __shared__ int s[256];
    int i = blockIdx.x * 256 + threadIdx.x;
    s[threadIdx.x] = (i < M_TOT) ? cnt[i] : 0;
    __syncthreads();
    for (int o = 128; o; o >>= 1) {
        if (threadIdx.x < o) s[threadIdx.x] += s[threadIdx.x + o];
        __syncthreads();
    }
    if (threadIdx.x == 0) bsums[blockIdx.x] = s[0];
}

// exclusive scan of bsums[NBLK] in-place, single block
__global__ void scan_bsums_kernel(int* __restrict__ b) {
    __shared__ int s[256];
    __shared__ int carry;
    if (threadIdx.x == 0) carry = 0;
    __syncthreads();
    for (int base = 0; base < NBLK; base += 256) {
        int i = base + threadIdx.x;
        int v = (i < NBLK) ? b[i] : 0;
        s[threadIdx.x] = v;
        __syncthreads();
        for (int o = 1; o < 256; o <<= 1) {          // Hillis-Steele inclusive
            int t = (threadIdx.x >= o) ? s[threadIdx.x - o] : 0;
            __syncthreads();
            s[threadIdx.x] += t;
            __syncthreads();
        }
        int excl = s[threadIdx.x] - v + carry;
        if (i < NBLK) b[i] = excl;
        __syncthreads();
        if (threadIdx.x == 0) carry += s[255];
        __syncthreads();
    }
}

// rs[i] = exclusive scan of cnt (+ rs[M_TOT] = total)
__global__ __launch_bounds__(256) void row_start_kernel(
    const int* __restrict__ cnt, const int* __restrict__ bsums,
    int* __restrict__ rs) {
    __shared__ int s[256];
    int i = blockIdx.x * 256 + threadIdx.x;
    int v = (i < M_TOT) ? cnt[i] : 0;
    s[threadIdx.x] = v;
    __syncthreads();
    for (int o = 1; o < 256; o <<= 1) {
        int t = (threadIdx.x >= o) ? s[threadIdx.x - o] : 0;
        __syncthreads();
        s[threadIdx.x] += t;
        __syncthreads();
    }
    int excl = s[threadIdx.x] - v + bsums[blockIdx.x];
    if (i < M_TOT) rs[i] = excl;
    if (i == M_TOT - 1) rs[M_TOT] = excl + v;
}

__global__ __launch_bounds__(256) void fill_kernel(
    const int* __restrict__ src, const int* __restrict__ dst,
    int* __restrict__ cursor, int* __restrict__ col) {
    int tid = blockIdx.x * 256 + threadIdx.x;
    if (tid >= NT * NE) return;
    int t = tid / NE;
    int slot = atomicAdd(&cursor[t * NN + dst[tid]], 1);
    col[slot] = src[tid];
}

// ---- fused per-layer kernel ------------------------------------------------
// Block = 64 nodes. Per etype t: stage W (128x64), gather-mean the 64 nodes'
// neighbors into LDS (wave-per-16-nodes, lane = feature), then 64x64 K=128
// register-tiled GEMM ([h_s | mean_s] @ [Ws; Wn]), bias+optional-relu into a
// persistent accumulator. Means never touch global; h staged once; out
// written once. LDS 66.8 KB -> 2 blocks/CU.
__global__ __launch_bounds__(256) void layer_kernel(
    const float* __restrict__ h, const int* __restrict__ rs,
    const int* __restrict__ col, const float* __restrict__ Wsl,
    const float* __restrict__ Wnl, const float* __restrict__ bias,
    float* __restrict__ out, int relu) {
    __shared__ __align__(16) float h_s[64][68];
    __shared__ __align__(16) float mean_s[64][68];
    __shared__ __align__(16) float W_s[128][64];

    const int tx = threadIdx.x;
    const int n0 = blockIdx.x * 64;
    const int rr = tx >> 4;          // 0..15
    const int k0 = (tx & 15) * 4;    // 0..60 step 4

    // ---- stage h tile (once) ----
#pragma unroll
    for (int q = 0; q < 4; ++q) {
        int r = rr + 16 * q;
        int n = n0 + r;
        float4 hv = make_float4(0.f, 0.f, 0.f, 0.f);
        if (n < NN) hv = *(const float4*)&h[(size_t)n * DD + k0];
        *(float4*)&h_s[r][k0] = hv;
    }

    const int lane = tx & 63, w = tx >> 6;
    const int c0 = (lane & 15) * 4;      // output cols c0..c0+3
    const int r0 = lane >> 4;            // 0..3
    const int rbase = w * 16 + r0;       // output rows rbase + 4*i
    const int f = lane;                  // gather feature lane

    float acc_sum[4][4];
#pragma unroll
    for (int i = 0; i < 4; ++i)
#pragma unroll
        for (int j = 0; j < 4; ++j) acc_sum[i][j] = 0.f;

    for (int t = 0; t < NT; ++t) {
        // ---- stage W tile: rows 0..63 = Ws_t, 64..127 = Wn_t ----
        const float* Ws = Wsl + (size_t)t * DD * DD;
        const float* Wn = Wnl + (size_t)t * DD * DD;
#pragma unroll
        for (int q = 0; q < 4; ++q) {
            int r = rr + 16 * q;
            *(float4*)&W_s[r][k0]      = *(const float4*)&Ws[(size_t)r * DD + k0];
            *(float4*)&W_s[64 + r][k0] = *(const float4*)&Wn[(size_t)r * DD + k0];
        }
        // ---- gather-mean: wave w builds rows w*16 .. w*16+15 ----
        for (int q = 0; q < 16; ++q) {
            int r = w * 16 + q;
            int n = n0 + r;
            float acc = 0.f;
            float invd = 0.f;
            if (n < NN) {
                int start = rs[t * NN + n], end = rs[t * NN + n + 1];
                int e = start;
                for (; e + 4 <= end; e += 4) {
                    int s0 = col[e], s1 = col[e + 1];
                    int s2 = col[e + 2], s3 = col[e + 3];
                    float v0 = h[(size_t)s0 * DD + f];
                    float v1 = h[(size_t)s1 * DD + f];
                    float v2 = h[(size_t)s2 * DD + f];
                    float v3 = h[(size_t)s3 * DD + f];
                    acc += (v0 + v1) + (v2 + v3);
                }
                for (; e < end; ++e) acc += h[(size_t)col[e] * DD + f];
                if (end > start) invd = 1.0f / (float)(end - start);
            }
            mean_s[r][f] = acc * invd;
        }
        __syncthreads();

        // ---- GEMM: acc_t = h_s@Ws + mean_s@Wn ----
        float acc_t[4][4];
#pragma unroll
        for (int i = 0; i < 4; ++i)
#pragma unroll
            for (int j = 0; j < 4; ++j) acc_t[i][j] = 0.f;

        for (int k = 0; k < 64; k += 4) {
            float4 av[4], wv[4];
#pragma unroll
            for (int i = 0; i < 4; ++i)
                av[i] = *(const float4*)&h_s[rbase + 4 * i][k];
#pragma unroll
            for (int kk = 0; kk < 4; ++kk)
                wv[kk] = *(const float4*)&W_s[k + kk][c0];
#pragma unroll
            for (int i = 0; i < 4; ++i) {
                const float* a = (const float*)&av[i];
#pragma unroll
                for (int kk = 0; kk < 4; ++kk) {
                    const float* ww = (const float*)&wv[kk];
                    acc_t[i][0] += a[kk] * ww[0];
                    acc_t[i][1] += a[kk] * ww[1];
                    acc_t[i][2] += a[kk] * ww[2];
                    acc_t[i][3] += a[kk] * ww[3];
                }
            }
        }
        for (int k = 0; k < 64; k += 4) {
            float4 av[4], wv[4];
#pragma unroll
            for (int i = 0; i < 4; ++i)
                av[i] = *(const float4*)&mean_s[rbase + 4 * i][k];
#pragma unroll
            for (int kk = 0; kk < 4; ++kk)
                wv[kk] = *(const float4*)&W_s[64 + k + kk][c0];
#pragma unroll
            for (int i = 0; i < 4; ++i) {
                const float* a = (const float*)&av[i];
#pragma unroll
                for (int kk = 0; kk < 4; ++kk) {
                    const float* ww = (const float*)&wv[kk];
                    acc_t[i][0] += a[kk] * ww[0];
                    acc_t[i][1] += a[kk] * ww[1];
                    acc_t[i][2] += a[kk] * ww[2];
                    acc_t[i][3] += a[kk] * ww[3];
                }
            }
        }

        // ---- bias + relu + cross-etype sum (registers only) ----
        float4 b4 = *(const float4*)&bias[t * DD + c0];
        const float* bb = (const float*)&b4;
#pragma unroll
        for (int i = 0; i < 4; ++i)
#pragma unroll
            for (int j = 0; j < 4; ++j) {
                float v = acc_t[i][j] + bb[j];
                if (relu) v = fmaxf(v, 0.f);
                acc_sum[i][j] += v;
            }
        __syncthreads();   // before next t overwrites mean_s / W_s
    }

    // ---- single coalesced out write ----
#pragma unroll
    for (int i = 0; i < 4; ++i) {
        int n = n0 + rbase + 4 * i;
        if (n >= NN) continue;
        float4 r4 = make_float4(acc_sum[i][0], acc_sum[i][1],
                                acc_sum[i][2], acc_sum[i][3]);
        *(float4*)&out[(size_t)n * DD + c0] = r4;
    }
}

extern "C" void kernel_launch(void* const* d_in, const int* in_sizes, int n_in,
                              void* d_out, int out_size, void* d_ws, size_t ws_size,
                              hipStream_t stream) {
    const float* feat    = (const float*)d_in[0];
    const float* W_self  = (const float*)d_in[1];
    const float* W_neigh = (const float*)d_in[2];
    const float* bias    = (const float*)d_in[3];
    const int* src = (const int*)d_in[4];
    const int* dst = (const int*)d_in[5];
    float* out = (float*)d_out;

    // ws layout (int-element offsets; ~34 MB total):
    //   cnt  [300000] @0 | rs [300008] @300000 | cursor [300000] @600008
    //   bsums[1184] @900008 | col [1200000] @901192 (pad) -> use 901184+8
    //   X f32[6.4M] @2101192-> keep 16B alignment
    int* base = (int*)d_ws;
    int* cnt    = base;
    int* rs     = base + 300000;
    int* cursor = base + 600008;
    int* bsums  = base + 900008;
    int* col    = base + 901184;
    float* X    = (float*)(base + 2101184);   // byte 8404736, 16B-aligned

    // ---- CSR build (once; reused across layers) ----
    hipMemsetAsync(cnt, 0, (size_t)M_TOT * sizeof(int), stream);
    count_kernel<<<(NT * NE + 255) / 256, 256, 0, stream>>>(dst, cnt);
    bsum_kernel<<<NBLK, 256, 0, stream>>>(cnt, bsums);
    scan_bsums_kernel<<<1, 256, 0, stream>>>(bsums);
    row_start_kernel<<<NBLK, 256, 0, stream>>>(cnt, bsums, rs);
    hipMemcpyAsync(cursor, rs, (size_t)M_TOT * sizeof(int),
                   hipMemcpyDeviceToDevice, stream);
    fill_kernel<<<(NT * NE + 255) / 256, 256, 0, stream>>>(src, dst, cursor, col);

    // layer dataflow: feat -> d_out -> X -> d_out (no intra-layer aliasing)
    const float* hin[NL]  = {feat, out, X};
    float*       hout[NL] = {out, X, out};
    const int lgrid = (NN + 63) / 64;

    for (int l = 0; l < NL; ++l) {
        layer_kernel<<<lgrid, 256, 0, stream>>>(
            hin[l], rs, col,
            W_self  + (size_t)l * NT * DD * DD,
            W_neigh + (size_t)l * NT * DD * DD,
            bias    + (size_t)l * NT * DD,
            hout[l], (l < NL - 1) ? 1 : 0);
    }
}

// Round 7
// 727.421 us; speedup vs baseline: 1.6903x; 1.6903x over previous
//
#include <hip/hip_runtime.h>
#include <hip/hip_bf16.h>

// Problem constants (match reference)
#define NN 100000   // nodes
#define NE 400000   // edges per etype
#define NT 3        // etypes
#define NL 3        // layers
#define DD 64       // feature dim
#define M_TOT (NT * NN)             // 300000 concatenated (etype,node) rows
#define NBLK ((M_TOT + 255) / 256)  // 1172 scan blocks

// Data established as fp32 (round-3 runtime dtype detection).
// Round-6 lesson: never fuse the latency-bound random gather into the
// LDS-heavy GEMM kernel (occupancy collapse). Keep gather standalone.

typedef __attribute__((ext_vector_type(8))) short bf16x8;  // 8 bf16 (4 VGPRs)
typedef __attribute__((ext_vector_type(4))) float f32x4;

static __device__ __forceinline__ unsigned short f2b(float f) {
    __hip_bfloat16 b = __float2bfloat16(f);
    return *reinterpret_cast<unsigned short*>(&b);
}

// ---- CSR build (once per launch; dst is layer-invariant) -------------------

__global__ __launch_bounds__(256) void count_kernel(const int* __restrict__ dst,
                                                    int* __restrict__ cnt) {
    int tid = blockIdx.x * 256 + threadIdx.x;
    if (tid >= NT * NE) return;
    int t = tid / NE;
    atomicAdd(&cnt[t * NN + dst[tid]], 1);
}

__global__ __launch_bounds__(256) void bsum_kernel(const int* __restrict__ cnt,
                                                   int* __restrict__ bsums) {
    __shared__ int s[256];
    int i = blockIdx.x * 256 + threadIdx.x;
    s[threadIdx.x] = (i < M_TOT) ? cnt[i] : 0;
    __syncthreads();
    for (int o = 128; o; o >>= 1) {
        if (threadIdx.x < o) s[threadIdx.x] += s[threadIdx.x + o];
        __syncthreads();
    }
    if (threadIdx.x == 0) bsums[blockIdx.x] = s[0];
}

__global__ void scan_bsums_kernel(int* __restrict__ b) {
    __shared__ int s[256];
    __shared__ int carry;
    if (threadIdx.x == 0) carry = 0;
    __syncthreads();
    for (int base = 0; base < NBLK; base += 256) {
        int i = base + threadIdx.x;
        int v = (i < NBLK) ? b[i] : 0;
        s[threadIdx.x] = v;
        __syncthreads();
        for (int o = 1; o < 256; o <<= 1) {
            int t = (threadIdx.x >= o) ? s[threadIdx.x - o] : 0;
            __syncthreads();
            s[threadIdx.x] += t;
            __syncthreads();
        }
        int excl = s[threadIdx.x] - v + carry;
        if (i < NBLK) b[i] = excl;
        __syncthreads();
        if (threadIdx.x == 0) carry += s[255];
        __syncthreads();
    }
}

__global__ __launch_bounds__(256) void row_start_kernel(
    const int* __restrict__ cnt, const int* __restrict__ bsums,
    int* __restrict__ rs) {
    __shared__ int s[256];
    int i = blockIdx.x * 256 + threadIdx.x;
    int v = (i < M_TOT) ? cnt[i] : 0;
    s[threadIdx.x] = v;
    __syncthreads();
    for (int o = 1; o < 256; o <<= 1) {
        int t = (threadIdx.x >= o) ? s[threadIdx.x - o] : 0;
        __syncthreads();
        s[threadIdx.x] += t;
        __syncthreads();
    }
    int excl = s[threadIdx.x] - v + bsums[blockIdx.x];
    if (i < M_TOT) rs[i] = excl;
    if (i == M_TOT - 1) rs[M_TOT] = excl + v;
}

__global__ __launch_bounds__(256) void fill_kernel(
    const int* __restrict__ src, const int* __restrict__ dst,
    int* __restrict__ cursor, int* __restrict__ col) {
    int tid = blockIdx.x * 256 + threadIdx.x;
    if (tid >= NT * NE) return;
    int t = tid / NE;
    int slot = atomicAdd(&cursor[t * NN + dst[tid]], 1);
    col[slot] = src[tid];
}

// ---- aggregation: pull-mode mean gather over ALL (etype,node) rows ---------
// wave-per-row (rs is the concatenated scan), lane = feature. h fp32 or bf16.
// Writes bf16 means (GEMM consumes bf16 anyway).
__global__ __launch_bounds__(256) void gather_kernel(
    const void* __restrict__ hv, int hbf, const int* __restrict__ rs,
    const int* __restrict__ col, __hip_bfloat16* __restrict__ meanb) {
    int i = blockIdx.x * 4 + (threadIdx.x >> 6);   // (etype,node) row
    if (i >= M_TOT) return;
    int f = threadIdx.x & 63;
    int start = rs[i], end = rs[i + 1];
    const float* hf = (const float*)hv;
    const __hip_bfloat16* hb = (const __hip_bfloat16*)hv;
    float acc = 0.f;
    int e = start;
    if (hbf) {
        for (; e + 4 <= end; e += 4) {
            int s0 = col[e], s1 = col[e + 1], s2 = col[e + 2], s3 = col[e + 3];
            float v0 = __bfloat162float(hb[(size_t)s0 * DD + f]);
            float v1 = __bfloat162float(hb[(size_t)s1 * DD + f]);
            float v2 = __bfloat162float(hb[(size_t)s2 * DD + f]);
            float v3 = __bfloat162float(hb[(size_t)s3 * DD + f]);
            acc += (v0 + v1) + (v2 + v3);
        }
        for (; e < end; ++e) acc += __bfloat162float(hb[(size_t)col[e] * DD + f]);
    } else {
        for (; e + 4 <= end; e += 4) {
            int s0 = col[e], s1 = col[e + 1], s2 = col[e + 2], s3 = col[e + 3];
            float v0 = hf[(size_t)s0 * DD + f];
            float v1 = hf[(size_t)s1 * DD + f];
            float v2 = hf[(size_t)s2 * DD + f];
            float v3 = hf[(size_t)s3 * DD + f];
            acc += (v0 + v1) + (v2 + v3);
        }
        for (; e < end; ++e) acc += hf[(size_t)col[e] * DD + f];
    }
    float invd = (end > start) ? 1.0f / (float)(end - start) : 0.f;
    meanb[(size_t)i * DD + f] = __float2bfloat16(acc * invd);
}

// ---- per-layer fused MFMA GEMM over all 3 etypes ---------------------------
// Block = 64 nodes x 64 cols, 4 waves. Per etype t: stage mean tile (bf16) and
// W'=[Ws;Wn]^T (bf16, transposed), 16x16x32 bf16 MFMA over K=128, bias+relu
// into persistent f32 accumulators; out written once. LDS 34 KB -> 4 blk/CU.
// Layouts (guide m89/m91/m120): A[m=lane&15][k=q*8+j], B[k=q*8+j][n=lane&15],
// C/D col=lane&15, row=q*4+reg.
__global__ __launch_bounds__(256) void layer_gemm(
    const void* __restrict__ hv, int hbf,
    const __hip_bfloat16* __restrict__ meanb,
    const float* __restrict__ Wsl, const float* __restrict__ Wnl,
    const float* __restrict__ bias, void* __restrict__ outv, int obf,
    int relu) {
    __shared__ short A_s[64 * 136];  // [row][k]: k<64 = h, k>=64 = mean
    __shared__ short B_s[64 * 136];  // [col j][k] = W'[k][j]

    const int tx = threadIdx.x;
    const int n0 = blockIdx.x * 64;
    const int lane = tx & 63, w = tx >> 6;
    const int q = lane >> 4, m16 = lane & 15;
    const int rr = tx >> 4;          // 0..15 (staging row group)
    const int k0 = (tx & 15) * 4;    // 0..60 step 4 (staging col)

    // ---- stage h tile once (f32->bf16 or bf16 passthrough) ----
#pragma unroll
    for (int qq = 0; qq < 4; ++qq) {
        int r = rr + 16 * qq;
        int n = n0 + r;
        ushort4 hb = make_ushort4(0, 0, 0, 0);
        if (n < NN) {
            if (hbf) {
                hb = *(const ushort4*)&((const unsigned short*)hv)[(size_t)n * DD + k0];
            } else {
                float4 hf = *(const float4*)&((const float*)hv)[(size_t)n * DD + k0];
                hb = make_ushort4(f2b(hf.x), f2b(hf.y), f2b(hf.z), f2b(hf.w));
            }
        }
        *(ushort4*)&A_s[r * 136 + k0] = hb;
    }

    float acc_sum[4][4];
#pragma unroll
    for (int c = 0; c < 4; ++c)
#pragma unroll
        for (int r = 0; r < 4; ++r) acc_sum[c][r] = 0.f;

    for (int t = 0; t < NT; ++t) {
        // ---- stage mean tile (already bf16) ----
#pragma unroll
        for (int qq = 0; qq < 4; ++qq) {
            int r = rr + 16 * qq;
            int n = n0 + r;
            ushort4 mv = make_ushort4(0, 0, 0, 0);
            if (n < NN)
                mv = *(const ushort4*)&((const unsigned short*)meanb)
                         [((size_t)t * NN + n) * DD + k0];
            *(ushort4*)&A_s[r * 136 + 64 + k0] = mv;
        }
        // ---- stage B_s[j][k] = W'[k][j], f32->bf16, transposed ----
        {
            const float* Ws = Wsl + (size_t)t * DD * DD;
            const float* Wn = Wnl + (size_t)t * DD * DD;
            int j = tx & 63, kb = tx >> 6;
            for (int k8 = 0; k8 < 128; k8 += 4) {
                int k = k8 + kb;
                float wv = (k < 64) ? Ws[(size_t)k * DD + j]
                                    : Wn[(size_t)(k - 64) * DD + j];
                B_s[j * 136 + k] = (short)f2b(wv);
            }
        }
        __syncthreads();

        // ---- MFMA: wave w -> rows 16w..16w+15, 4 col-tiles, K=128 ----
        f32x4 acc[4];
#pragma unroll
        for (int c = 0; c < 4; ++c) acc[c] = (f32x4){0.f, 0.f, 0.f, 0.f};
#pragma unroll
        for (int kt = 0; kt < 4; ++kt) {
            bf16x8 a = *(const bf16x8*)&A_s[(16 * w + m16) * 136 + kt * 32 + q * 8];
#pragma unroll
            for (int c = 0; c < 4; ++c) {
                bf16x8 b = *(const bf16x8*)&B_s[(c * 16 + m16) * 136 + kt * 32 + q * 8];
                acc[c] = __builtin_amdgcn_mfma_f32_16x16x32_bf16(a, b, acc[c], 0, 0, 0);
            }
        }

        // ---- bias + relu + cross-etype sum (registers) ----
#pragma unroll
        for (int c = 0; c < 4; ++c) {
            float bv = bias[t * DD + c * 16 + m16];
#pragma unroll
            for (int r = 0; r < 4; ++r) {
                float v = acc[c][r] + bv;
                if (relu) v = fmaxf(v, 0.f);
                acc_sum[c][r] += v;
            }
        }
        __syncthreads();  // before next t overwrites A_s mean region / B_s
    }

    // ---- single out write: row = n0+16w+q*4+r, col = c*16+m16 ----
#pragma unroll
    for (int c = 0; c < 4; ++c)
#pragma unroll
        for (int r = 0; r < 4; ++r) {
            int n = n0 + 16 * w + q * 4 + r;
            if (n >= NN) continue;
            size_t idx = (size_t)n * DD + c * 16 + m16;
            if (obf)
                ((__hip_bfloat16*)outv)[idx] = __float2bfloat16(acc_sum[c][r]);
            else
                ((float*)outv)[idx] = acc_sum[c][r];
        }
}

extern "C" void kernel_launch(void* const* d_in, const int* in_sizes, int n_in,
                              void* d_out, int out_size, void* d_ws, size_t ws_size,
                              hipStream_t stream) {
    const float* feat    = (const float*)d_in[0];
    const float* W_self  = (const float*)d_in[1];
    const float* W_neigh = (const float*)d_in[2];
    const float* bias    = (const float*)d_in[3];
    const int* src = (const int*)d_in[4];
    const int* dst = (const int*)d_in[5];

    // ws layout (int-element offsets; 59.6 MB total, proven footprint):
    //   cnt[300000]@0 | rs[300008]@300000 | cursor[300000]@600008
    //   bsums[1184]@900008 | col[1200000]@901200
    //   meanb bf16[3*NN*DD]@2101200 (byte 8404800, 16B-aligned)
    //   X     bf16[NN*DD] @11701200 (byte 46804800, 16B-aligned)
    int* base = (int*)d_ws;
    int* cnt    = base;
    int* rs     = base + 300000;
    int* cursor = base + 600008;
    int* bsums  = base + 900008;
    int* col    = base + 901200;
    __hip_bfloat16* meanb = (__hip_bfloat16*)(base + 2101200);
    __hip_bfloat16* X     = (__hip_bfloat16*)(base + 11701200);

    // ---- CSR build (once; reused across layers) ----
    hipMemsetAsync(cnt, 0, (size_t)M_TOT * sizeof(int), stream);
    count_kernel<<<(NT * NE + 255) / 256, 256, 0, stream>>>(dst, cnt);
    bsum_kernel<<<NBLK, 256, 0, stream>>>(cnt, bsums);
    scan_bsums_kernel<<<1, 256, 0, stream>>>(bsums);
    row_start_kernel<<<NBLK, 256, 0, stream>>>(cnt, bsums, rs);
    hipMemcpyAsync(cursor, rs, (size_t)M_TOT * sizeof(int),
                   hipMemcpyDeviceToDevice, stream);
    fill_kernel<<<(NT * NE + 255) / 256, 256, 0, stream>>>(src, dst, cursor, col);

    // layer dataflow: feat(f32) -> d_out(f32) -> X(bf16) -> d_out(f32)
    const void* hin[NL]  = {feat, d_out, X};
    const int  hbf[NL]   = {0, 0, 1};
    void*      hout[NL]  = {d_out, X, d_out};
    const int  obf[NL]   = {0, 1, 0};
    const int ggrid = (M_TOT + 3) / 4;
    const int mgrid = (NN + 63) / 64;

    for (int l = 0; l < NL; ++l) {
        gather_kernel<<<ggrid, 256, 0, stream>>>(hin[l], hbf[l], rs, col, meanb);
        layer_gemm<<<mgrid, 256, 0, stream>>>(
            hin[l], hbf[l], meanb,
            W_self  + (size_t)l * NT * DD * DD,
            W_neigh + (size_t)l * NT * DD * DD,
            bias    + (size_t)l * NT * DD,
            hout[l], obf[l], (l < NL - 1) ? 1 : 0);
    }
}

// Round 8
// 508.244 us; speedup vs baseline: 2.4192x; 1.4312x over previous
//
#include <hip/hip_runtime.h>
#include <hip/hip_bf16.h>

// Problem constants (match reference)
#define NN 100000   // nodes
#define NE 400000   // edges per etype
#define NT 3        // etypes
#define NL 3        // layers
#define DD 64       // feature dim
#define M_TOT (NT * NN)             // 300000 concatenated (etype,node) rows
#define NBLK ((M_TOT + 255) / 256)  // 1172 scan blocks

// Data established as fp32 (round-3 runtime dtype detection).
// Round-6 lesson: never fuse the latency-bound random gather into the
// LDS-heavy GEMM kernel (occupancy collapse). Keep gather standalone.
// Round-7 lesson: gather is transaction/latency-bound, not byte-bound
// (bf16 h showed identical FETCH and dur) -> attack latency serialization.

typedef __attribute__((ext_vector_type(8))) short bf16x8;  // 8 bf16 (4 VGPRs)
typedef __attribute__((ext_vector_type(4))) float f32x4;

static __device__ __forceinline__ unsigned short f2b(float f) {
    __hip_bfloat16 b = __float2bfloat16(f);
    return *reinterpret_cast<unsigned short*>(&b);
}
static __device__ __forceinline__ float b2f(unsigned short u) {
    __hip_bfloat16 b = *reinterpret_cast<__hip_bfloat16*>(&u);
    return __bfloat162float(b);
}

// ---- CSR build (once per launch; dst is layer-invariant) -------------------

__global__ __launch_bounds__(256) void count_kernel(const int* __restrict__ dst,
                                                    int* __restrict__ cnt) {
    int tid = blockIdx.x * 256 + threadIdx.x;
    if (tid >= NT * NE) return;
    int t = tid / NE;
    atomicAdd(&cnt[t * NN + dst[tid]], 1);
}

__global__ __launch_bounds__(256) void bsum_kernel(const int* __restrict__ cnt,
                                                   int* __restrict__ bsums) {
    __shared__ int s[256];
    int i = blockIdx.x * 256 + threadIdx.x;
    s[threadIdx.x] = (i < M_TOT) ? cnt[i] : 0;
    __syncthreads();
    for (int o = 128; o; o >>= 1) {
        if (threadIdx.x < o) s[threadIdx.x] += s[threadIdx.x + o];
        __syncthreads();
    }
    if (threadIdx.x == 0) bsums[blockIdx.x] = s[0];
}

__global__ void scan_bsums_kernel(int* __restrict__ b) {
    __shared__ int s[256];
    __shared__ int carry;
    if (threadIdx.x == 0) carry = 0;
    __syncthreads();
    for (int base = 0; base < NBLK; base += 256) {
        int i = base + threadIdx.x;
        int v = (i < NBLK) ? b[i] : 0;
        s[threadIdx.x] = v;
        __syncthreads();
        for (int o = 1; o < 256; o <<= 1) {
            int t = (threadIdx.x >= o) ? s[threadIdx.x - o] : 0;
            __syncthreads();
            s[threadIdx.x] += t;
            __syncthreads();
        }
        int excl = s[threadIdx.x] - v + carry;
        if (i < NBLK) b[i] = excl;
        __syncthreads();
        if (threadIdx.x == 0) carry += s[255];
        __syncthreads();
    }
}

__global__ __launch_bounds__(256) void row_start_kernel(
    const int* __restrict__ cnt, const int* __restrict__ bsums,
    int* __restrict__ rs) {
    __shared__ int s[256];
    int i = blockIdx.x * 256 + threadIdx.x;
    int v = (i < M_TOT) ? cnt[i] : 0;
    s[threadIdx.x] = v;
    __syncthreads();
    for (int o = 1; o < 256; o <<= 1) {
        int t = (threadIdx.x >= o) ? s[threadIdx.x - o] : 0;
        __syncthreads();
        s[threadIdx.x] += t;
        __syncthreads();
    }
    int excl = s[threadIdx.x] - v + bsums[blockIdx.x];
    if (i < M_TOT) rs[i] = excl;
    if (i == M_TOT - 1) rs[M_TOT] = excl + v;
}

__global__ __launch_bounds__(256) void fill_kernel(
    const int* __restrict__ src, const int* __restrict__ dst,
    int* __restrict__ cursor, int* __restrict__ col) {
    int tid = blockIdx.x * 256 + threadIdx.x;
    if (tid >= NT * NE) return;
    int t = tid / NE;
    int slot = atomicAdd(&cursor[t * NN + dst[tid]], 1);
    col[slot] = src[tid];
}

// ---- one-time weight transpose: Wt[lt][j][k] = bf16(W'[k][j]) --------------
// W' = [Ws ; Wn] (K=128). Contiguous in k for vector B-staging in layer_gemm.
__global__ __launch_bounds__(256) void wtrans_kernel(
    const float* __restrict__ Ws, const float* __restrict__ Wn,
    unsigned short* __restrict__ Wt) {
    int lt = blockIdx.x;   // 0..8
    for (int p = threadIdx.x; p < DD * 2 * DD; p += 256) {
        int j = p >> 7, k = p & 127;
        float v = (k < DD) ? Ws[(size_t)lt * DD * DD + k * DD + j]
                           : Wn[(size_t)lt * DD * DD + (k - DD) * DD + j];
        Wt[(size_t)lt * 8192 + j * 128 + k] = f2b(v);
    }
}

// ---- aggregation: pull-mode mean gather, predicated 8-wide -----------------
// wave-per-(etype,node)-row, lane = feature. All 8 loads per iteration are
// independent; OOB slots re-read neighbor 0 (cache hit) with a x0 mask.
template <int HBF>
__global__ __launch_bounds__(256) void gather_kernel(
    const void* __restrict__ hv, const int* __restrict__ rs,
    const int* __restrict__ col, unsigned short* __restrict__ meanb) {
    int i = blockIdx.x * 4 + (threadIdx.x >> 6);
    if (i >= M_TOT) return;
    int f = threadIdx.x & 63;
    int start = rs[i], end = rs[i + 1];
    int deg = end - start;
    float acc = 0.f;
    if (deg > 0) {
        const float* hf = (const float*)hv;
        const unsigned short* hb = (const unsigned short*)hv;
        for (int e = start; e < end; e += 8) {
            int idx[8];
            float msk[8];
#pragma unroll
            for (int u = 0; u < 8; ++u) {
                int ee = e + u;
                bool valid = ee < end;
                idx[u] = col[valid ? ee : start];
                msk[u] = valid ? 1.f : 0.f;
            }
            float vv[8];
#pragma unroll
            for (int u = 0; u < 8; ++u)
                vv[u] = HBF ? b2f(hb[(size_t)idx[u] * DD + f])
                            : hf[(size_t)idx[u] * DD + f];
#pragma unroll
            for (int u = 0; u < 8; ++u) acc += msk[u] * vv[u];
        }
        acc /= (float)deg;
    }
    meanb[(size_t)i * DD + f] = f2b(acc);
}

// ---- per-layer fused MFMA GEMM over all 3 etypes ---------------------------
// Block = 64 nodes x 64 cols, 4 waves. Per etype t: stage mean tile (bf16) +
// pre-transposed W' tile (vector copy), 16x16x32 bf16 MFMA over K=128,
// bias+relu into persistent f32 accumulators; out written once.
// LDS 34.8 KB -> 4 blocks/CU. Layouts verified in round 7.
template <int HBF, int OBF>
__global__ __launch_bounds__(256) void layer_gemm(
    const void* __restrict__ hv, const unsigned short* __restrict__ meanb,
    const unsigned short* __restrict__ Wt, const float* __restrict__ bias,
    void* __restrict__ outv, int relu) {
    __shared__ __align__(16) short A_s[64 * 136];  // [row][k]: k<64 h, k>=64 mean
    __shared__ __align__(16) short B_s[64 * 136];  // [col j][k]

    const int tx = threadIdx.x;
    const int n0 = blockIdx.x * 64;
    const int lane = tx & 63, w = tx >> 6;
    const int q = lane >> 4, m16 = lane & 15;
    const int rr = tx >> 4;          // 0..15 (staging row group)
    const int k0 = (tx & 15) * 4;    // 0..60 step 4 (staging col)
    const int bj = tx >> 2;          // 0..63 (B staging row)
    const int bk = (tx & 3) * 32;    // 0,32,64,96

    // ---- stage h tile once ----
#pragma unroll
    for (int qq = 0; qq < 4; ++qq) {
        int r = rr + 16 * qq;
        int n = n0 + r;
        ushort4 hb4 = make_ushort4(0, 0, 0, 0);
        if (n < NN) {
            if (HBF) {
                hb4 = *(const ushort4*)&((const unsigned short*)hv)[(size_t)n * DD + k0];
            } else {
                float4 hf = *(const float4*)&((const float*)hv)[(size_t)n * DD + k0];
                hb4 = make_ushort4(f2b(hf.x), f2b(hf.y), f2b(hf.z), f2b(hf.w));
            }
        }
        *(ushort4*)&A_s[r * 136 + k0] = hb4;
    }

    float acc_sum[4][4];
#pragma unroll
    for (int c = 0; c < 4; ++c)
#pragma unroll
        for (int r = 0; r < 4; ++r) acc_sum[c][r] = 0.f;

    for (int t = 0; t < NT; ++t) {
        // ---- stage mean tile (bf16) ----
#pragma unroll
        for (int qq = 0; qq < 4; ++qq) {
            int r = rr + 16 * qq;
            int n = n0 + r;
            ushort4 mv = make_ushort4(0, 0, 0, 0);
            if (n < NN)
                mv = *(const ushort4*)&meanb[((size_t)t * NN + n) * DD + k0];
            *(ushort4*)&A_s[r * 136 + 64 + k0] = mv;
        }
        // ---- stage B tile: 16B vector copies from pre-transposed Wt ----
        {
            const unsigned short* wt = Wt + (size_t)t * 8192 + bj * 128 + bk;
#pragma unroll
            for (int u = 0; u < 4; ++u)
                *(int4*)&B_s[bj * 136 + bk + u * 8] = *(const int4*)&wt[u * 8];
        }
        __syncthreads();

        // ---- MFMA: wave w -> rows 16w..16w+15, 4 col-tiles, K=128 ----
        f32x4 acc[4];
#pragma unroll
        for (int c = 0; c < 4; ++c) acc[c] = (f32x4){0.f, 0.f, 0.f, 0.f};
#pragma unroll
        for (int kt = 0; kt < 4; ++kt) {
            bf16x8 a = *(const bf16x8*)&A_s[(16 * w + m16) * 136 + kt * 32 + q * 8];
#pragma unroll
            for (int c = 0; c < 4; ++c) {
                bf16x8 b = *(const bf16x8*)&B_s[(c * 16 + m16) * 136 + kt * 32 + q * 8];
                acc[c] = __builtin_amdgcn_mfma_f32_16x16x32_bf16(a, b, acc[c], 0, 0, 0);
            }
        }

        // ---- bias + relu + cross-etype sum (registers) ----
#pragma unroll
        for (int c = 0; c < 4; ++c) {
            float bv = bias[t * DD + c * 16 + m16];
#pragma unroll
            for (int r = 0; r < 4; ++r) {
                float v = acc[c][r] + bv;
                if (relu) v = fmaxf(v, 0.f);
                acc_sum[c][r] += v;
            }
        }
        __syncthreads();  // before next t overwrites A_s mean region / B_s
    }

    // ---- single out write: row = n0+16w+q*4+r, col = c*16+m16 ----
#pragma unroll
    for (int c = 0; c < 4; ++c)
#pragma unroll
        for (int r = 0; r < 4; ++r) {
            int n = n0 + 16 * w + q * 4 + r;
            if (n >= NN) continue;
            size_t idx = (size_t)n * DD + c * 16 + m16;
            if (OBF)
                ((unsigned short*)outv)[idx] = f2b(acc_sum[c][r]);
            else
                ((float*)outv)[idx] = acc_sum[c][r];
        }
}

extern "C" void kernel_launch(void* const* d_in, const int* in_sizes, int n_in,
                              void* d_out, int out_size, void* d_ws, size_t ws_size,
                              hipStream_t stream) {
    const float* feat    = (const float*)d_in[0];
    const float* W_self  = (const float*)d_in[1];
    const float* W_neigh = (const float*)d_in[2];
    const float* bias    = (const float*)d_in[3];
    const int* src = (const int*)d_in[4];
    const int* dst = (const int*)d_in[5];

    // ws layout (int-element offsets; ~59.8 MB total):
    //   cnt[300000]@0 | rs[300008]@300000 | cursor[300000]@600008
    //   bsums[1184]@900008 | col[1200000]@901200
    //   Wt    u16[73728]     @int 2101200 (byte 8404800, 16B-aligned)
    //   meanb u16[3*NN*DD]   @int 2138064 (byte 8552256, 16B-aligned)
    //   X     u16[NN*DD]     @int 11738064 (byte 46952256, 16B-aligned)
    int* base = (int*)d_ws;
    int* cnt    = base;
    int* rs     = base + 300000;
    int* cursor = base + 600008;
    int* bsums  = base + 900008;
    int* col    = base + 901200;
    unsigned short* Wt    = (unsigned short*)(base + 2101200);
    unsigned short* meanb = (unsigned short*)(base + 2138064);
    unsigned short* X     = (unsigned short*)(base + 11738064);

    // ---- CSR build + weight transpose (once; reused across layers) ----
    hipMemsetAsync(cnt, 0, (size_t)M_TOT * sizeof(int), stream);
    count_kernel<<<(NT * NE + 255) / 256, 256, 0, stream>>>(dst, cnt);
    bsum_kernel<<<NBLK, 256, 0, stream>>>(cnt, bsums);
    scan_bsums_kernel<<<1, 256, 0, stream>>>(bsums);
    row_start_kernel<<<NBLK, 256, 0, stream>>>(cnt, bsums, rs);
    hipMemcpyAsync(cursor, rs, (size_t)M_TOT * sizeof(int),
                   hipMemcpyDeviceToDevice, stream);
    fill_kernel<<<(NT * NE + 255) / 256, 256, 0, stream>>>(src, dst, cursor, col);
    wtrans_kernel<<<NL * NT, 256, 0, stream>>>(W_self, W_neigh, Wt);

    // layer dataflow: feat(f32) -> d_out(f32) -> X(bf16) -> d_out(f32)
    float* outf = (float*)d_out;
    const int ggrid = (M_TOT + 3) / 4;
    const int mgrid = (NN + 63) / 64;

    // layer 1: feat f32 -> d_out f32 (relu)
    gather_kernel<0><<<ggrid, 256, 0, stream>>>(feat, rs, col, meanb);
    layer_gemm<0, 0><<<mgrid, 256, 0, stream>>>(
        feat, meanb, Wt + 0 * NT * 8192, bias + 0 * NT * DD, outf, 1);
    // layer 2: d_out f32 -> X bf16 (relu)
    gather_kernel<0><<<ggrid, 256, 0, stream>>>(outf, rs, col, meanb);
    layer_gemm<0, 1><<<mgrid, 256, 0, stream>>>(
        outf, meanb, Wt + 1 * NT * 8192, bias + 1 * NT * DD, X, 1);
    // layer 3: X bf16 -> d_out f32 (no relu)
    gather_kernel<1><<<ggrid, 256, 0, stream>>>(X, rs, col, meanb);
    layer_gemm<1, 0><<<mgrid, 256, 0, stream>>>(
        X, meanb, Wt + 2 * NT * 8192, bias + 2 * NT * DD, outf, 0);
}

// Round 10
// 439.631 us; speedup vs baseline: 2.7967x; 1.1561x over previous
//
#include <hip/hip_runtime.h>
#include <hip/hip_bf16.h>

// Problem constants (match reference)
#define NN 100000   // nodes
#define NE 400000   // edges per etype
#define NT 3        // etypes
#define NL 3        // layers
#define DD 64       // feature dim
#define M_TOT (NT * NN)             // 300000 concatenated (etype,node) rows
#define RPB 2048                    // rows per bucket (row >> 11)
#define NBKT ((M_TOT + RPB - 1) / RPB)   // 147 buckets
#define P3CAP 32                    // LDS pairs per bucket in pair_scatter
#define P3GRID 256                  // pair_scatter grid (capacity slack depends on it)
#define OVF_CAP 1200000             // ovf region capacity (uint2 entries)

// Data established as fp32 (round-3 runtime dtype detection).
// Round-6 lesson: never fuse the latency-bound random gather into the
// LDS-heavy GEMM kernel (occupancy collapse). Keep gather standalone.
// Round-7 lesson: gather is transaction-bound, not byte-bound.
// Round-8 lesson: scattered 4B stores amplify ~16x at HBM -> CSR writes must
// be line-grouped or block-owned.
// Round-9 lesson (crash): per-bucket pair capacity MUST include per-block
// sentinel padding (each of P3GRID blocks pads its drain to 16).

typedef __attribute__((ext_vector_type(8))) short bf16x8;  // 8 bf16 (4 VGPRs)
typedef __attribute__((ext_vector_type(4))) float f32x4;

static __device__ __forceinline__ unsigned short f2b(float f) {
    __hip_bfloat16 b = __float2bfloat16(f);
    return *reinterpret_cast<unsigned short*>(&b);
}
static __device__ __forceinline__ float b2f(unsigned short u) {
    __hip_bfloat16 b = *reinterpret_cast<__hip_bfloat16*>(&u);
    return __bfloat162float(b);
}

// ---- P1: per-bucket edge counts (LDS histogram) ----------------------------
__global__ __launch_bounds__(256) void bucket_count(const int* __restrict__ dst,
                                                    int* __restrict__ bcnt) {
    __shared__ int h[NBKT];
    for (int i = threadIdx.x; i < NBKT; i += 256) h[i] = 0;
    __syncthreads();
    const int total = NT * NE;
    for (int e = blockIdx.x * 256 + threadIdx.x; e < total; e += gridDim.x * 256) {
        int t = e / NE;
        int row = t * NN + dst[e];
        atomicAdd(&h[row >> 11], 1);
    }
    __syncthreads();
    for (int i = threadIdx.x; i < NBKT; i += 256)
        if (h[i]) atomicAdd(&bcnt[i], h[i]);
}

// ---- P2: bucket scans ------------------------------------------------------
// ebase: tight scan (rs/col). pbase: padded scan for pair regions — capacity
// per bucket = round16(cnt) + 16*P3GRID (every pair_scatter block may drain
// one sentinel-padded group into every bucket). THIS is the round-9 fix.
__global__ void bucket_scan(const int* __restrict__ bcnt, int* __restrict__ ebase,
                            int* __restrict__ pbase, int* __restrict__ gcur,
                            int* __restrict__ ocnt, int* __restrict__ rs) {
    __shared__ int s[256], s2[256];
    int v = (threadIdx.x < NBKT) ? bcnt[threadIdx.x] : 0;
    int pv = ((v + 15) & ~15) + 16 * P3GRID;
    s[threadIdx.x] = v; s2[threadIdx.x] = pv;
    __syncthreads();
    for (int o = 1; o < 256; o <<= 1) {
        int a = (threadIdx.x >= o) ? s[threadIdx.x - o] : 0;
        int b = (threadIdx.x >= o) ? s2[threadIdx.x - o] : 0;
        __syncthreads();
        s[threadIdx.x] += a; s2[threadIdx.x] += b;
        __syncthreads();
    }
    if (threadIdx.x < NBKT) {
        ebase[threadIdx.x] = s[threadIdx.x] - v;
        int pb = s2[threadIdx.x] - pv;
        pbase[threadIdx.x] = pb;
        gcur[threadIdx.x] = pb;
    }
    if (threadIdx.x == 0) { ocnt[0] = 0; rs[M_TOT] = NT * NE; }
}

// ---- P3: scatter packed pairs into bucket regions via LDS line-grouping ----
// pair = (row_local<<17)|src (src<2^17). Global writes only as aligned 64B
// groups of 16 pairs; drains pad with sentinel 0xFFFFFFFF (src field >= NN)
// so gcur stays 16-aligned. Overflow (cap exceeded) -> ovf side list.
__global__ __launch_bounds__(256) void pair_scatter(
    const int* __restrict__ src, const int* __restrict__ dst,
    int* __restrict__ gcur, unsigned* __restrict__ pairs,
    uint2* __restrict__ ovf, int* __restrict__ ocnt) {
    __shared__ unsigned buf[NBKT][P3CAP];   // 18.8 KB
    __shared__ int fill[NBKT];
    for (int i = threadIdx.x; i < NBKT; i += 256) fill[i] = 0;
    __syncthreads();
    const int total = NT * NE;
    int per = (total + gridDim.x - 1) / gridDim.x;
    int beg = blockIdx.x * per;
    int fin = beg + per; if (fin > total) fin = total;
    for (int bse = beg; bse < fin; bse += 256) {
        int e = bse + threadIdx.x;
        if (e < fin) {
            int t = e / NE;
            int row = t * NN + dst[e];
            int bk = row >> 11;
            unsigned pr = ((unsigned)(row & 2047) << 17) | (unsigned)src[e];
            int pos = atomicAdd(&fill[bk], 1);
            if (pos < P3CAP) buf[bk][pos] = pr;
            else {
                int o = atomicAdd(ocnt, 1);
                if (o < OVF_CAP) ovf[o] = make_uint2((unsigned)src[e], (unsigned)row);
            }
        }
        __syncthreads();
        for (int bk = threadIdx.x; bk < NBKT; bk += 256) {
            int n = fill[bk]; if (n > P3CAP) n = P3CAP;
            int g = n >> 4;
            if (g) {
                int gb = atomicAdd(&gcur[bk], g * 16);
#pragma unroll
                for (int q = 0; q < 4; ++q)   // group 0
                    *(int4*)&pairs[gb + q * 4] = *(const int4*)&buf[bk][q * 4];
                if (g == 2)
#pragma unroll
                    for (int q = 0; q < 4; ++q)
                        *(int4*)&pairs[gb + 16 + q * 4] =
                            *(const int4*)&buf[bk][16 + q * 4];
                int rem = n - g * 16;
                for (int k = 0; k < rem; ++k) buf[bk][k] = buf[bk][g * 16 + k];
                fill[bk] = rem;
            } else fill[bk] = n;
        }
        __syncthreads();
    }
    // drain: pad to 16 with sentinels to keep gcur 64B-aligned
    for (int bk = threadIdx.x; bk < NBKT; bk += 256) {
        int n = fill[bk]; if (n > P3CAP) n = P3CAP;
        if (n) {
            int m = (n + 15) & ~15;
            for (int k = n; k < m; ++k) buf[bk][k] = 0xFFFFFFFFu;
            int gb = atomicAdd(&gcur[bk], m);
            for (int grp = 0; grp < m >> 4; ++grp)
#pragma unroll
                for (int q = 0; q < 4; ++q)
                    *(int4*)&pairs[gb + grp * 16 + q * 4] =
                        *(const int4*)&buf[bk][grp * 16 + q * 4];
        }
    }
}

// ---- P4: per-bucket CSR finalize (block-owned rs/col regions) --------------
__global__ __launch_bounds__(256) void bucket_csr(
    const int* __restrict__ ebase, const int* __restrict__ pbase,
    const int* __restrict__ gcur, const unsigned* __restrict__ pairs,
    const uint2* __restrict__ ovf, const int* __restrict__ ocnt,
    int* __restrict__ rs, int* __restrict__ col) {
    __shared__ int cnt_s[RPB];
    __shared__ int cur_s[RPB];
    __shared__ int part[256];
    int b = blockIdx.x;
    int row0 = b << 11;
    int nrows = M_TOT - row0; if (nrows > RPB) nrows = RPB;
    for (int i = threadIdx.x; i < RPB; i += 256) cnt_s[i] = 0;
    __syncthreads();
    int pb = pbase[b], pe = gcur[b];
    for (int p = pb + threadIdx.x; p < pe; p += 256) {
        unsigned pr = pairs[p];
        if ((pr & 0x1FFFFu) < NN) atomicAdd(&cnt_s[pr >> 17], 1);
    }
    int no = ocnt[0]; if (no > OVF_CAP) no = OVF_CAP;
    for (int o = threadIdx.x; o < no; o += 256) {
        int rl = (int)ovf[o].y - row0;
        if (rl >= 0 && rl < nrows) atomicAdd(&cnt_s[rl], 1);
    }
    __syncthreads();
    int t0 = threadIdx.x * 8, sum = 0;
    int exl[8];
#pragma unroll
    for (int k = 0; k < 8; ++k) { exl[k] = sum; sum += cnt_s[t0 + k]; }
    part[threadIdx.x] = sum;
    __syncthreads();
    for (int o = 1; o < 256; o <<= 1) {
        int v = (threadIdx.x >= o) ? part[threadIdx.x - o] : 0;
        __syncthreads();
        part[threadIdx.x] += v;
        __syncthreads();
    }
    int off = part[threadIdx.x] - sum + ebase[b];
#pragma unroll
    for (int k = 0; k < 8; ++k) {
        int idx = t0 + k;
        int ex = exl[k] + off;
        cur_s[idx] = ex;
        if (idx < nrows) rs[row0 + idx] = ex;
    }
    __syncthreads();
    for (int p = pb + threadIdx.x; p < pe; p += 256) {
        unsigned pr = pairs[p];
        unsigned s = pr & 0x1FFFFu;
        if (s < NN) {
            int pos = atomicAdd(&cur_s[pr >> 17], 1);
            col[pos] = (int)s;
        }
    }
    for (int o = threadIdx.x; o < no; o += 256) {
        int rl = (int)ovf[o].y - row0;
        if (rl >= 0 && rl < nrows) {
            int pos = atomicAdd(&cur_s[rl], 1);
            col[pos] = (int)ovf[o].x;
        }
    }
}

// ---- one-time weight transpose: Wt[lt][j][k] = bf16(W'[k][j]), K=128 -------
__global__ __launch_bounds__(256) void wtrans_kernel(
    const float* __restrict__ Ws, const float* __restrict__ Wn,
    unsigned short* __restrict__ Wt) {
    int lt = blockIdx.x;   // 0..8
    for (int p = threadIdx.x; p < DD * 2 * DD; p += 256) {
        int j = p >> 7, k = p & 127;
        float v = (k < DD) ? Ws[(size_t)lt * DD * DD + k * DD + j]
                           : Wn[(size_t)lt * DD * DD + (k - DD) * DD + j];
        Wt[(size_t)lt * 8192 + j * 128 + k] = f2b(v);
    }
}

// ---- aggregation: pull-mode mean gather, predicated 8-wide -----------------
template <int HBF>
__global__ __launch_bounds__(256) void gather_kernel(
    const void* __restrict__ hv, const int* __restrict__ rs,
    const int* __restrict__ col, unsigned short* __restrict__ meanb) {
    int i = blockIdx.x * 4 + (threadIdx.x >> 6);
    if (i >= M_TOT) return;
    int f = threadIdx.x & 63;
    int start = rs[i], end = rs[i + 1];
    int deg = end - start;
    float acc = 0.f;
    if (deg > 0) {
        const float* hf = (const float*)hv;
        const unsigned short* hb = (const unsigned short*)hv;
        for (int e = start; e < end; e += 8) {
            int idx[8];
            float msk[8];
#pragma unroll
            for (int u = 0; u < 8; ++u) {
                int ee = e + u;
                bool valid = ee < end;
                idx[u] = col[valid ? ee : start];
                msk[u] = valid ? 1.f : 0.f;
            }
            float vv[8];
#pragma unroll
            for (int u = 0; u < 8; ++u)
                vv[u] = HBF ? b2f(hb[(size_t)idx[u] * DD + f])
                            : hf[(size_t)idx[u] * DD + f];
#pragma unroll
            for (int u = 0; u < 8; ++u) acc += msk[u] * vv[u];
        }
        acc /= (float)deg;
    }
    meanb[(size_t)i * DD + f] = f2b(acc);
}

// ---- per-layer fused MFMA GEMM over all 3 etypes (round-7/8 verified) ------
template <int HBF, int OBF>
__global__ __launch_bounds__(256) void layer_gemm(
    const void* __restrict__ hv, const unsigned short* __restrict__ meanb,
    const unsigned short* __restrict__ Wt, const float* __restrict__ bias,
    void* __restrict__ outv, int relu) {
    __shared__ __align__(16) short A_s[64 * 136];  // [row][k]: k<64 h, k>=64 mean
    __shared__ __align__(16) short B_s[64 * 136];  // [col j][k]

    const int tx = threadIdx.x;
    const int n0 = blockIdx.x * 64;
    const int lane = tx & 63, w = tx >> 6;
    const int q = lane >> 4, m16 = lane & 15;
    const int rr = tx >> 4;
    const int k0 = (tx & 15) * 4;
    const int bj = tx >> 2;
    const int bk = (tx & 3) * 32;

#pragma unroll
    for (int qq = 0; qq < 4; ++qq) {
        int r = rr + 16 * qq;
        int n = n0 + r;
        ushort4 hb4 = make_ushort4(0, 0, 0, 0);
        if (n < NN) {
            if (HBF) {
                hb4 = *(const ushort4*)&((const unsigned short*)hv)[(size_t)n * DD + k0];
            } else {
                float4 hf = *(const float4*)&((const float*)hv)[(size_t)n * DD + k0];
                hb4 = make_ushort4(f2b(hf.x), f2b(hf.y), f2b(hf.z), f2b(hf.w));
            }
        }
        *(ushort4*)&A_s[r * 136 + k0] = hb4;
    }

    float acc_sum[4][4];
#pragma unroll
    for (int c = 0; c < 4; ++c)
#pragma unroll
        for (int r = 0; r < 4; ++r) acc_sum[c][r] = 0.f;

    for (int t = 0; t < NT; ++t) {
#pragma unroll
        for (int qq = 0; qq < 4; ++qq) {
            int r = rr + 16 * qq;
            int n = n0 + r;
            ushort4 mv = make_ushort4(0, 0, 0, 0);
            if (n < NN)
                mv = *(const ushort4*)&meanb[((size_t)t * NN + n) * DD + k0];
            *(ushort4*)&A_s[r * 136 + 64 + k0] = mv;
        }
        {
            const unsigned short* wt = Wt + (size_t)t * 8192 + bj * 128 + bk;
#pragma unroll
            for (int u = 0; u < 4; ++u)
                *(int4*)&B_s[bj * 136 + bk + u * 8] = *(const int4*)&wt[u * 8];
        }
        __syncthreads();

        f32x4 acc[4];
#pragma unroll
        for (int c = 0; c < 4; ++c) acc[c] = (f32x4){0.f, 0.f, 0.f, 0.f};
#pragma unroll
        for (int kt = 0; kt < 4; ++kt) {
            bf16x8 a = *(const bf16x8*)&A_s[(16 * w + m16) * 136 + kt * 32 + q * 8];
#pragma unroll
            for (int c = 0; c < 4; ++c) {
                bf16x8 b = *(const bf16x8*)&B_s[(c * 16 + m16) * 136 + kt * 32 + q * 8];
                acc[c] = __builtin_amdgcn_mfma_f32_16x16x32_bf16(a, b, acc[c], 0, 0, 0);
            }
        }

#pragma unroll
        for (int c = 0; c < 4; ++c) {
            float bv = bias[t * DD + c * 16 + m16];
#pragma unroll
            for (int r = 0; r < 4; ++r) {
                float v = acc[c][r] + bv;
                if (relu) v = fmaxf(v, 0.f);
                acc_sum[c][r] += v;
            }
        }
        __syncthreads();
    }

#pragma unroll
    for (int c = 0; c < 4; ++c)
#pragma unroll
        for (int r = 0; r < 4; ++r) {
            int n = n0 + 16 * w + q * 4 + r;
            if (n >= NN) continue;
            size_t idx = (size_t)n * DD + c * 16 + m16;
            if (OBF)
                ((unsigned short*)outv)[idx] = f2b(acc_sum[c][r]);
            else
                ((float*)outv)[idx] = acc_sum[c][r];
        }
}

extern "C" void kernel_launch(void* const* d_in, const int* in_sizes, int n_in,
                              void* d_out, int out_size, void* d_ws, size_t ws_size,
                              hipStream_t stream) {
    const float* feat    = (const float*)d_in[0];
    const float* W_self  = (const float*)d_in[1];
    const float* W_neigh = (const float*)d_in[2];
    const float* bias    = (const float*)d_in[3];
    const int* src = (const int*)d_in[4];
    const int* dst = (const int*)d_in[5];

    // ws layout (byte offsets; max 57.4 MB <= proven 59.75 MB):
    //   bcnt@0 ebase@1024 pbase@2048 gcur@3072 ocnt@4096 (small)
    //   rs   @8192        (1,200,004 B)
    //   col  @1,208,320   (4.8 MB)
    //   Wt   @6,008,320   (147,456 B)
    //   X2   @6,155,776   (12.8 MB bf16)
    //   meanb@18,955,776  (38.4 MB bf16)
    //   pairs = alias of meanb      (<=7.22 MB incl. slack, dead after P4)
    //   ovf   = meanb + 10,485,760  (<=9.6 MB, dead after P4)
    char* ws = (char*)d_ws;
    int* bcnt  = (int*)(ws + 0);
    int* ebase = (int*)(ws + 1024);
    int* pbase = (int*)(ws + 2048);
    int* gcur  = (int*)(ws + 3072);
    int* ocnt  = (int*)(ws + 4096);
    int* rs    = (int*)(ws + 8192);
    int* col   = (int*)(ws + 1208320);
    unsigned short* Wt    = (unsigned short*)(ws + 6008320);
    unsigned short* X2    = (unsigned short*)(ws + 6155776);
    unsigned short* meanb = (unsigned short*)(ws + 18955776);
    unsigned*       pairs = (unsigned*)(ws + 18955776);
    uint2*          ovf   = (uint2*)(ws + 18955776 + 10485760);

    // ---- CSR build (bucket-local, line-grouped writes) ----
    hipMemsetAsync(bcnt, 0, NBKT * sizeof(int), stream);
    bucket_count<<<512, 256, 0, stream>>>(dst, bcnt);
    bucket_scan<<<1, 256, 0, stream>>>(bcnt, ebase, pbase, gcur, ocnt, rs);
    pair_scatter<<<P3GRID, 256, 0, stream>>>(src, dst, gcur, pairs, ovf, ocnt);
    bucket_csr<<<NBKT, 256, 0, stream>>>(ebase, pbase, gcur, pairs, ovf, ocnt,
                                         rs, col);
    wtrans_kernel<<<NL * NT, 256, 0, stream>>>(W_self, W_neigh, Wt);

    // layer dataflow: feat(f32) -> X1 bf16 (in d_out) -> X2 bf16 (ws)
    //                 -> d_out f32 (final; overwrites dead X1)
    unsigned short* X1 = (unsigned short*)d_out;
    const int ggrid = (M_TOT + 3) / 4;
    const int mgrid = (NN + 63) / 64;

    gather_kernel<0><<<ggrid, 256, 0, stream>>>(feat, rs, col, meanb);
    layer_gemm<0, 1><<<mgrid, 256, 0, stream>>>(
        feat, meanb, Wt + 0 * NT * 8192, bias + 0 * NT * DD, X1, 1);
    gather_kernel<1><<<ggrid, 256, 0, stream>>>(X1, rs, col, meanb);
    layer_gemm<1, 1><<<mgrid, 256, 0, stream>>>(
        X1, meanb, Wt + 1 * NT * 8192, bias + 1 * NT * DD, X2, 1);
    gather_kernel<1><<<ggrid, 256, 0, stream>>>(X2, rs, col, meanb);
    layer_gemm<1, 0><<<mgrid, 256, 0, stream>>>(
        X2, meanb, Wt + 2 * NT * 8192, bias + 2 * NT * DD, d_out, 0);
}